// Round 7
// baseline (260.846 us; speedup 1.0000x reference)
//
#include <hip/hip_runtime.h>
#include <hip/hip_bf16.h>
#include <stdint.h>

#define DIM 1024
#define NH 16
#define NKV 4
#define HD 64
#define SEQ 2048
#define BATCH 2
#define RANK 4
#define NSTEPS 2

// bf16 conversion-region element offsets (compile-time)
#define XN      4194304            // x: 4096*1024
#define WQ_END  5242880            // + 1024*1024
#define WK_END  5505024            // + 256*1024
#define WV_END  5767168            // + 256*1024
#define CVT_BLOCKS 6656
#define LORA_BLOCKS 1024

typedef unsigned short u16;
typedef unsigned int u32;
typedef __attribute__((ext_vector_type(8))) __bf16 bf16x8;
typedef __attribute__((ext_vector_type(4))) float f32x4;

__device__ __forceinline__ float bf2f(u16 v) {
    u32 u = ((u32)v) << 16;
    return __builtin_bit_cast(float, u);
}
__device__ __forceinline__ u16 f2bf(float f) {
    u32 u = __builtin_bit_cast(u32, f);
    u32 r = (u + 0x7fffu + ((u >> 16) & 1u)) >> 16;
    return (u16)r;
}
__device__ __forceinline__ u32 pk2(float a, float b) {
    return (u32)f2bf(a) | ((u32)f2bf(b) << 16);
}
// async global->LDS, 16 B per lane; lptr MUST be wave-uniform (HW adds lane*16)
__device__ __forceinline__ void glds16(const u16* g, u16* l) {
    __builtin_amdgcn_global_load_lds(
        (const __attribute__((address_space(1))) u32*)g,
        (__attribute__((address_space(3))) u32*)l, 16, 0, 0);
}

// ---------------- K_PREP: fused [fp32->bf16 convert | LoRA t = x@A^T] -------
__global__ __launch_bounds__(256) void k_prep(
    const float* __restrict__ x, const float* __restrict__ Wq,
    const float* __restrict__ Wk, const float* __restrict__ Wv,
    const float* __restrict__ Wp, u16* __restrict__ dst,
    const float* __restrict__ Aq, const float* __restrict__ Av,
    const int* __restrict__ step_p, float* __restrict__ tq, float* __restrict__ tv)
{
    int bx = blockIdx.x;
    if (bx < CVT_BLOCKS) {
        int e = (bx * 256 + threadIdx.x) * 4;
        const float* src;
        if (e < XN)          src = x  + e;
        else if (e < WQ_END) src = Wq + (e - XN);
        else if (e < WK_END) src = Wk + (e - WQ_END);
        else if (e < WV_END) src = Wv + (e - WK_END);
        else                 src = Wp + (e - WV_END);
        float4 v = *(const float4*)src;
        *(uint2*)(dst + e) = make_uint2(pk2(v.x, v.y), pk2(v.z, v.w));
        return;
    }
    int wave = ((bx - CVT_BLOCKS) * 256 + threadIdx.x) >> 6;
    int lane = threadIdx.x & 63;
    int step = step_p[0];
    int valid = (step >= 0 && step < NSTEPS);
    int sc = valid ? step : 0;
    const float* xr = x + wave * DIM + lane * 16;
    float xf[16];
#pragma unroll
    for (int q = 0; q < 4; q++) {
        float4 v4 = *(const float4*)(xr + q * 4);
        xf[q * 4 + 0] = v4.x; xf[q * 4 + 1] = v4.y;
        xf[q * 4 + 2] = v4.z; xf[q * 4 + 3] = v4.w;
    }
    float sums[8];
#pragma unroll
    for (int j = 0; j < 8; j++) {
        const float* ar = (j < 4 ? Aq + sc * RANK * DIM + j * DIM
                                 : Av + sc * RANK * DIM + (j - 4) * DIM) + lane * 16;
        float s = 0.f;
#pragma unroll
        for (int q = 0; q < 4; q++) {
            float4 a4 = *(const float4*)(ar + q * 4);
            s += xf[q * 4 + 0] * a4.x + xf[q * 4 + 1] * a4.y
               + xf[q * 4 + 2] * a4.z + xf[q * 4 + 3] * a4.w;
        }
#pragma unroll
        for (int o = 32; o > 0; o >>= 1) s += __shfl_xor(s, o, 64);
        sums[j] = s;
    }
    if (!valid) {
#pragma unroll
        for (int j = 0; j < 8; j++) sums[j] = 0.f;
    }
    if (lane == 0) {
        tq[wave * 4 + 0] = sums[0]; tq[wave * 4 + 1] = sums[1];
        tq[wave * 4 + 2] = sums[2]; tq[wave * 4 + 3] = sums[3];
        tv[wave * 4 + 0] = sums[4]; tv[wave * 4 + 1] = sums[5];
        tv[wave * 4 + 2] = sums[6]; tv[wave * 4 + 3] = sums[7];
    }
}

// ---------------- GEMM: 128x64 tile, BK=64, m97-style single-buffer + glds16.
// C[M][N] = A[M][1024] * B[N][1024]^T. 4 waves in 2x2; wave = 64 rows x 32 cols.
template<bool CF32>
__global__ __launch_bounds__(256) void k_gemm(
    const u16* __restrict__ A, const u16* __restrict__ B,
    void* __restrict__ Cptr, int Ntiles, int N)
{
    __shared__ __align__(16) u16 As[8192];   // (mt*2+c)*64+lane chunks, mt 0..7
    __shared__ __align__(16) u16 Bs[4096];   // (nt*2+c)*64+lane chunks, nt 0..3
    int bx = blockIdx.x;
    int bn = bx % Ntiles, bm = bx / Ntiles;
    int t = threadIdx.x, lane = t & 63, w = t >> 6;
    int wy = w >> 1, wx = w & 1;
    int wb = t & ~63;                 // w*64, wave-uniform
    f32x4 acc[4][2];
#pragma unroll
    for (int i = 0; i < 4; i++)
#pragma unroll
        for (int j = 0; j < 2; j++) acc[i][j] = (f32x4){0.f, 0.f, 0.f, 0.f};

    // frag-linear chunk global offsets: idx -> row=(grp>>1)*16+m, c=grp&1
    int goffA[4], goffB[2];
#pragma unroll
    for (int u = 0; u < 4; u++) {
        int idx = u * 256 + t;
        int grp = idx >> 6;
        int quad = (idx >> 4) & 3, m = idx & 15;
        goffA[u] = ((grp >> 1) * 16 + m) * DIM + (grp & 1) * 32 + quad * 8;
    }
#pragma unroll
    for (int u = 0; u < 2; u++) {
        int idx = u * 256 + t;
        int grp = idx >> 6;
        int quad = (idx >> 4) & 3, m = idx & 15;
        goffB[u] = ((grp >> 1) * 16 + m) * DIM + (grp & 1) * 32 + quad * 8;
    }
    const u16* Ab = A + bm * 128 * DIM;
    const u16* Bb = B + bn * 64 * DIM;

#pragma unroll 1
    for (int kb = 0; kb < 16; kb++) {
        int k0 = kb * 64;
        __syncthreads();
#pragma unroll
        for (int u = 0; u < 4; u++)
            glds16(Ab + goffA[u] + k0, As + (u * 256 + wb) * 8);
#pragma unroll
        for (int u = 0; u < 2; u++)
            glds16(Bb + goffB[u] + k0, Bs + (u * 256 + wb) * 8);
        __syncthreads();
#pragma unroll
        for (int c = 0; c < 2; c++) {
            bf16x8 af[4], bfr[2];
#pragma unroll
            for (int i = 0; i < 4; i++) {
                int mt = wy * 4 + i;
                af[i] = *(bf16x8*)(As + ((mt * 2 + c) * 64 + lane) * 8);
            }
#pragma unroll
            for (int j = 0; j < 2; j++) {
                int nt = wx * 2 + j;
                bfr[j] = *(bf16x8*)(Bs + ((nt * 2 + c) * 64 + lane) * 8);
            }
#pragma unroll
            for (int i = 0; i < 4; i++)
#pragma unroll
                for (int j = 0; j < 2; j++)
                    acc[i][j] = __builtin_amdgcn_mfma_f32_16x16x32_bf16(af[i], bfr[j], acc[i][j], 0, 0, 0);
        }
    }
    int quad = lane >> 4, n16 = lane & 15;
#pragma unroll
    for (int i = 0; i < 4; i++) {
#pragma unroll
        for (int j = 0; j < 2; j++) {
            int col = bn * 64 + wx * 32 + j * 16 + n16;
#pragma unroll
            for (int r = 0; r < 4; r++) {
                int rowm = bm * 128 + wy * 64 + i * 16 + quad * 4 + r;
                if (CF32) ((float*)Cptr)[rowm * N + col] = acc[i][j][r];
                else      ((u16*)Cptr)[rowm * N + col] = f2bf(acc[i][j][r]);
            }
        }
    }
}

// ---------------- K_POST: fused [RMSNorm+RoPE in-place | v-LoRA+transpose] ---
#define NR_BLOCKS 20480
__global__ __launch_bounds__(256) void k_post(
    u16* __restrict__ qkv,
    const float* __restrict__ tq, const float* __restrict__ Bq,
    const float* __restrict__ gain,
    const float* __restrict__ tv, const float* __restrict__ Bv,
    const int* __restrict__ step_p, u16* __restrict__ vt)
{
    __shared__ __align__(16) u16 tile[64 * 64];
    int bx = blockIdx.x;
    int step = step_p[0];
    int valid = (step >= 0 && step < NSTEPS);
    int sc = valid ? step : 0;
    if (bx < NR_BLOCKS) {
        int wid = (bx * 256 + threadIdx.x) >> 6;
        int lane = threadIdx.x & 63;
        float val, postmul;
        u16* ptr;
        int s;
        if (wid < BATCH * NH * SEQ) {
            int b = wid >> 15;
            int h = (wid >> 11) & 15;
            s = wid & 2047;
            int row = b * SEQ + s;
            ptr = qkv + row * 1536 + h * HD + lane;
            val = bf2f(*ptr);
            const float* tr = tq + row * 4;
            float4 br = *(const float4*)(Bq + sc * DIM * RANK + (h * HD + lane) * RANK);
            val += tr[0] * br.x + tr[1] * br.y + tr[2] * br.z + tr[3] * br.w;
            postmul = gain[h] * 0.125f * 1.4426950408889634f;   // gain/sqrt(64)*log2e
        } else {
            int wk = wid - BATCH * NH * SEQ;
            int b = wk >> 13;
            int h = (wk >> 11) & 3;
            s = wk & 2047;
            int row = b * SEQ + s;
            ptr = qkv + row * 1536 + 1024 + h * HD + lane;
            val = bf2f(*ptr);
            postmul = 1.f;
        }
        float ss = val * val;
#pragma unroll
        for (int o = 32; o > 0; o >>= 1) ss += __shfl_xor(ss, o, 64);
        float rr = rsqrtf(ss * (1.f / 64.f) + 1.1920928955078125e-7f);
        float vn = val * rr;
        float partner = __shfl_xor(vn, 16, 64);
        float res;
        if (lane < 32) {
            int i = lane & 15;
            float invf = exp2f(-(float)i * 0.8304820237218405f);  // log2(10000)/16
            float ang = (float)s * invf;
            float cs = cosf(ang), sn = sinf(ang);
            res = (lane < 16) ? (vn * cs + partner * sn) : (-partner * sn + vn * cs);
        } else {
            res = vn;
        }
        *ptr = f2bf(res * postmul);
        return;
    }
    // ---- v transpose path ----
    int vb = bx - NR_BLOCKS;
    int st = vb & 31, g = (vb >> 5) & 3, b = vb >> 7;
    int t = threadIdx.x;
    int s_l = t & 63, dq = t >> 6;
    int row = b * SEQ + st * 64 + s_l;
    const float* tr = tv + row * 4;
    float t0 = tr[0], t1 = tr[1], t2 = tr[2], t3 = tr[3];
    const u16* src = qkv + row * 1536 + 1280 + g * HD + dq * 16;
#pragma unroll
    for (int e = 0; e < 16; e++) {
        int d = dq * 16 + e;
        float4 br = *(const float4*)(Bv + sc * (NKV * HD) * RANK + (g * HD + d) * RANK);
        float v = bf2f(src[e]) + t0 * br.x + t1 * br.y + t2 * br.z + t3 * br.w;
        tile[d * 64 + s_l] = f2bf(v);
    }
    __syncthreads();
#pragma unroll
    for (int u = 0; u < 2; u++) {
        int chunk = u * 256 + t;
        int d = chunk >> 3, scn = chunk & 7;
        *(uint4*)(vt + ((b * NKV + g) * HD + d) * SEQ + st * 64 + scn * 8) =
            *(uint4*)(tile + d * 64 + scn * 8);
    }
}

// ---------------- ATT: static-max flash attention, balanced block pairs -----
// Block = (b,h,qtsel) processes q-tiles qtsel AND 31-qtsel sequentially ->
// exactly 33 K-tile iterations per block (uniform makespan, no tail).
// K/V staged via global_load_lds into XOR-swizzled LDS; static M = 11.67|gain|.
__global__ __launch_bounds__(256) void k_attn(
    const u16* __restrict__ qkv, const u16* __restrict__ vt,
    const float* __restrict__ gain, u16* __restrict__ y)
{
    __shared__ __align__(16) u16 kf[4096];       // [64 keys][8 chunks^swz]
    __shared__ __align__(16) u16 vf[4096];       // [64 d][8 chunks^swz]
    __shared__ __align__(16) u16 pb[4][1024];    // per-wave P^T, B-frag linear
    int bx = blockIdx.x;
    int qtsel = bx & 31;
    int h = (bx >> 5) & 15, b = bx >> 9;
    int g = h >> 2;
    int t = threadIdx.x, lane = t & 63, w = t >> 6, wb = t & ~63;
    int quad = lane >> 4, n16 = lane & 15;
    float negM = -11.67f * fabsf(gain[h]);       // static softmax max bound

    const u16* kbase = qkv + b * SEQ * 1536 + 1024 + g * HD;   // K rows stride 1536
    const u16* vbase = vt + (b * NKV + g) * HD * SEQ;          // V^T rows stride 2048

    // staging slot offsets: slot s holds row r=s>>3, global chunk c=(s&7)^(r&7)
    int koff[2], voff[2];
#pragma unroll
    for (int i = 0; i < 2; i++) {
        int s = i * 256 + t;
        int r = s >> 3, cc = s & 7;
        int c = cc ^ (r & 7);
        koff[i] = r * 1536 + c * 8;
        voff[i] = r * 2048 + c * 8;
    }
    // frag-read swizzled chunk offsets (16-B slots)
    int swb = n16 & 7;
    int o0 = n16 * 8 + (quad ^ swb);
    int o1 = n16 * 8 + ((4 + quad) ^ swb);
    u16* pw = pb[w];

#pragma unroll 1
    for (int ph = 0; ph < 2; ph++) {
        int qt = ph ? (31 - qtsel) : qtsel;
        int qrow = qt * 64 + w * 16 + n16;
        const u16* qp = qkv + (b * SEQ + qrow) * 1536 + h * HD + quad * 8;
        bf16x8 qlo = *(const bf16x8*)qp;
        bf16x8 qhi = *(const bf16x8*)(qp + 32);
        f32x4 acc[4];
#pragma unroll
        for (int i = 0; i < 4; i++) acc[i] = (f32x4){0.f, 0.f, 0.f, 0.f};
        float ps = 0.f;
        int ntiles = qt + 1;

#pragma unroll 1
        for (int kt = 0; kt < ntiles; kt++) {
            int k0 = kt * 64;
            __syncthreads();                      // prior tile's LDS reads done
            const u16* kp = kbase + k0 * 1536;
            const u16* vp = vbase + k0;
            glds16(kp + koff[0], kf + wb * 8);
            glds16(kp + koff[1], kf + (256 + wb) * 8);
            glds16(vp + voff[0], vf + wb * 8);
            glds16(vp + voff[1], vf + (256 + wb) * 8);
            __syncthreads();                      // vmcnt drained at barrier
            // S^T = K * Q^T : D[key][q]
            f32x4 st[4];
#pragma unroll
            for (int nt = 0; nt < 4; nt++) {
                f32x4 sa = (f32x4){0.f, 0.f, 0.f, 0.f};
                sa = __builtin_amdgcn_mfma_f32_16x16x32_bf16(*(bf16x8*)(kf + (nt * 128 + o0) * 8), qlo, sa, 0, 0, 0);
                sa = __builtin_amdgcn_mfma_f32_16x16x32_bf16(*(bf16x8*)(kf + (nt * 128 + o1) * 8), qhi, sa, 0, 0, 0);
                st[nt] = sa;
            }
            // p = exp2(s - M); causal zero on diagonal tile
            float p[4][4];
            if (kt == ntiles - 1) {
#pragma unroll
                for (int nt = 0; nt < 4; nt++)
#pragma unroll
                    for (int r = 0; r < 4; r++) {
                        int key = k0 + nt * 16 + quad * 4 + r;
                        float e = exp2f(st[nt][r] + negM);
                        e = (key > qrow) ? 0.f : e;
                        p[nt][r] = e;
                        ps += e;
                    }
            } else {
#pragma unroll
                for (int nt = 0; nt < 4; nt++)
#pragma unroll
                    for (int r = 0; r < 4; r++) {
                        float e = exp2f(st[nt][r] + negM);
                        p[nt][r] = e;
                        ps += e;
                    }
            }
            // P^T -> per-wave LDS in B-frag linear layout
#pragma unroll
            for (int nt = 0; nt < 4; nt++) {
                u32 lo = pk2(p[nt][0], p[nt][1]);
                u32 hi = pk2(p[nt][2], p[nt][3]);
                int ck = nt >> 1;
                int qbk = (nt & 1) * 2 + (quad >> 1);
                int byteoff = (ck * 64 + qbk * 16 + n16) * 16 + (quad & 1) * 8;
                *(uint2*)((char*)pw + byteoff) = make_uint2(lo, hi);
            }
            asm volatile("s_waitcnt lgkmcnt(0)" ::: "memory");
            // Y^T += V^T * P^T
#pragma unroll
            for (int ck = 0; ck < 2; ck++) {
                bf16x8 pfr = *(bf16x8*)(pw + (ck * 64 + lane) * 8);
                int oo = ck ? o1 : o0;
#pragma unroll
                for (int dt = 0; dt < 4; dt++)
                    acc[dt] = __builtin_amdgcn_mfma_f32_16x16x32_bf16(*(bf16x8*)(vf + (dt * 128 + oo) * 8), pfr, acc[dt], 0, 0, 0);
            }
            asm volatile("" ::: "memory");
        }
        // final l per q-col: in-lane ps + across the 4 quads holding this col
        float pt = ps + __shfl_xor(ps, 16, 64);
        pt += __shfl_xor(pt, 32, 64);
        float li = 1.f / pt;
#pragma unroll
        for (int dt = 0; dt < 4; dt++) {
            uint2 o = make_uint2(pk2(acc[dt][0] * li, acc[dt][1] * li),
                                 pk2(acc[dt][2] * li, acc[dt][3] * li));
            int d = dt * 16 + quad * 4;
            *(uint2*)(y + (b * SEQ + qrow) * DIM + h * HD + d) = o;
        }
        ps = 0.f;
    }
}

// ---------------------------------------------------------------------------
extern "C" void kernel_launch(void* const* d_in, const int* in_sizes, int n_in,
                              void* d_out, int out_size, void* d_ws, size_t ws_size,
                              hipStream_t stream)
{
    (void)in_sizes; (void)n_in; (void)out_size; (void)ws_size;
    const float* x     = (const float*)d_in[0];
    const float* Wq    = (const float*)d_in[1];
    const float* Wk    = (const float*)d_in[2];
    const float* Wv    = (const float*)d_in[3];
    const float* Wproj = (const float*)d_in[4];
    const float* qgain = (const float*)d_in[5];
    const float* Aq    = (const float*)d_in[6];
    const float* Bq    = (const float*)d_in[7];
    const float* Av    = (const float*)d_in[8];
    const float* Bv    = (const float*)d_in[9];
    const int*   step  = (const int*)d_in[10];

    // ws layout (25.1 MB): cvt [xb 8MB | Wqkv 3MB | Wproj 2MB] + qkv 12MB + tq/tv
    // reuse: y overlays xb; vt overlays Wqkv.
    char* ws = (char*)d_ws;
    u16* wsbf = (u16*)ws;
    u16* xb   = wsbf;
    u16* wf   = wsbf + XN;
    u16* wp   = wsbf + WV_END;
    u16* qkv  = (u16*)(ws + 13631488);
    float* tq = (float*)(ws + 26214400);
    float* tv = tq + 16384;
    u16* y    = xb;
    u16* vt   = wf;

    k_prep<<<CVT_BLOCKS + LORA_BLOCKS, 256, 0, stream>>>(x, Wq, Wk, Wv, Wproj, wsbf,
                                                         Aq, Av, step, tq, tv);
    k_gemm<false><<<768, 256, 0, stream>>>(xb, wf, qkv, 24, 1536);      // fused qkv
    k_post<<<NR_BLOCKS + 256, 256, 0, stream>>>(qkv, tq, Bq, qgain, tv, Bv, step, vt);
    k_attn<<<1024, 256, 0, stream>>>(qkv, vt, qgain, y);
    k_gemm<true><<<512, 256, 0, stream>>>(y, wp, d_out, 16, DIM);       // out proj
}

// Round 8
// 256.142 us; speedup vs baseline: 1.0184x; 1.0184x over previous
//
#include <hip/hip_runtime.h>
#include <hip/hip_bf16.h>
#include <stdint.h>

#define DIM 1024
#define NH 16
#define NKV 4
#define HD 64
#define SEQ 2048
#define BATCH 2
#define RANK 4
#define NSTEPS 2

// bf16 conversion-region element offsets (compile-time)
#define XN      4194304            // x: 4096*1024
#define WQ_END  5242880            // + 1024*1024
#define WK_END  5505024            // + 256*1024
#define WV_END  5767168            // + 256*1024
#define CVT_BLOCKS 6656
#define LORA_BLOCKS 1024

typedef unsigned short u16;
typedef unsigned int u32;
typedef __attribute__((ext_vector_type(8))) __bf16 bf16x8;
typedef __attribute__((ext_vector_type(4))) float f32x4;

__device__ __forceinline__ float bf2f(u16 v) {
    u32 u = ((u32)v) << 16;
    return __builtin_bit_cast(float, u);
}
__device__ __forceinline__ u16 f2bf(float f) {
    u32 u = __builtin_bit_cast(u32, f);
    u32 r = (u + 0x7fffu + ((u >> 16) & 1u)) >> 16;
    return (u16)r;
}
__device__ __forceinline__ u32 pk2(float a, float b) {
    return (u32)f2bf(a) | ((u32)f2bf(b) << 16);
}
// async global->LDS, 16 B per lane; lptr MUST be wave-uniform (HW adds lane*16)
__device__ __forceinline__ void glds16(const u16* g, u16* l) {
    __builtin_amdgcn_global_load_lds(
        (const __attribute__((address_space(1))) u32*)g,
        (__attribute__((address_space(3))) u32*)l, 16, 0, 0);
}

// ---------------- K_PREP: fused [fp32->bf16 convert | LoRA t = x@A^T] -------
__global__ __launch_bounds__(256) void k_prep(
    const float* __restrict__ x, const float* __restrict__ Wq,
    const float* __restrict__ Wk, const float* __restrict__ Wv,
    const float* __restrict__ Wp, u16* __restrict__ dst,
    const float* __restrict__ Aq, const float* __restrict__ Av,
    const int* __restrict__ step_p, float* __restrict__ tq, float* __restrict__ tv)
{
    int bx = blockIdx.x;
    if (bx < CVT_BLOCKS) {
        int e = (bx * 256 + threadIdx.x) * 4;
        const float* src;
        if (e < XN)          src = x  + e;
        else if (e < WQ_END) src = Wq + (e - XN);
        else if (e < WK_END) src = Wk + (e - WQ_END);
        else if (e < WV_END) src = Wv + (e - WK_END);
        else                 src = Wp + (e - WV_END);
        float4 v = *(const float4*)src;
        *(uint2*)(dst + e) = make_uint2(pk2(v.x, v.y), pk2(v.z, v.w));
        return;
    }
    int wave = ((bx - CVT_BLOCKS) * 256 + threadIdx.x) >> 6;
    int lane = threadIdx.x & 63;
    int step = step_p[0];
    int valid = (step >= 0 && step < NSTEPS);
    int sc = valid ? step : 0;
    const float* xr = x + wave * DIM + lane * 16;
    float xf[16];
#pragma unroll
    for (int q = 0; q < 4; q++) {
        float4 v4 = *(const float4*)(xr + q * 4);
        xf[q * 4 + 0] = v4.x; xf[q * 4 + 1] = v4.y;
        xf[q * 4 + 2] = v4.z; xf[q * 4 + 3] = v4.w;
    }
    float sums[8];
#pragma unroll
    for (int j = 0; j < 8; j++) {
        const float* ar = (j < 4 ? Aq + sc * RANK * DIM + j * DIM
                                 : Av + sc * RANK * DIM + (j - 4) * DIM) + lane * 16;
        float s = 0.f;
#pragma unroll
        for (int q = 0; q < 4; q++) {
            float4 a4 = *(const float4*)(ar + q * 4);
            s += xf[q * 4 + 0] * a4.x + xf[q * 4 + 1] * a4.y
               + xf[q * 4 + 2] * a4.z + xf[q * 4 + 3] * a4.w;
        }
#pragma unroll
        for (int o = 32; o > 0; o >>= 1) s += __shfl_xor(s, o, 64);
        sums[j] = s;
    }
    if (!valid) {
#pragma unroll
        for (int j = 0; j < 8; j++) sums[j] = 0.f;
    }
    if (lane == 0) {
        tq[wave * 4 + 0] = sums[0]; tq[wave * 4 + 1] = sums[1];
        tq[wave * 4 + 2] = sums[2]; tq[wave * 4 + 3] = sums[3];
        tv[wave * 4 + 0] = sums[4]; tv[wave * 4 + 1] = sums[5];
        tv[wave * 4 + 2] = sums[6]; tv[wave * 4 + 3] = sums[7];
    }
}

// ---------------- GEMM: 128x64 tile, BK=64, DOUBLE-buffered LDS images with
// ONE barrier per K-step: stage(k+1) issued right after the barrier so its
// vmcnt drain happens a full compute-phase later (overlapped).
template<bool CF32>
__global__ __launch_bounds__(256) void k_gemm(
    const u16* __restrict__ A, const u16* __restrict__ B,
    void* __restrict__ Cptr, int Ntiles, int N)
{
    __shared__ __align__(16) u16 As[2][8192];
    __shared__ __align__(16) u16 Bs[2][4096];
    int bx = blockIdx.x;
    int bn = bx % Ntiles, bm = bx / Ntiles;
    int t = threadIdx.x, lane = t & 63, w = t >> 6;
    int wy = w >> 1, wx = w & 1;
    int wb = t & ~63;                 // w*64, wave-uniform
    f32x4 acc[4][2];
#pragma unroll
    for (int i = 0; i < 4; i++)
#pragma unroll
        for (int j = 0; j < 2; j++) acc[i][j] = (f32x4){0.f, 0.f, 0.f, 0.f};

    int goffA[4], goffB[2];
#pragma unroll
    for (int u = 0; u < 4; u++) {
        int idx = u * 256 + t;
        int grp = idx >> 6;
        int quad = (idx >> 4) & 3, m = idx & 15;
        goffA[u] = ((grp >> 1) * 16 + m) * DIM + (grp & 1) * 32 + quad * 8;
    }
#pragma unroll
    for (int u = 0; u < 2; u++) {
        int idx = u * 256 + t;
        int grp = idx >> 6;
        int quad = (idx >> 4) & 3, m = idx & 15;
        goffB[u] = ((grp >> 1) * 16 + m) * DIM + (grp & 1) * 32 + quad * 8;
    }
    const u16* Ab = A + bm * 128 * DIM;
    const u16* Bb = B + bn * 64 * DIM;

    // stage kb=0 into image 0
#pragma unroll
    for (int u = 0; u < 4; u++) glds16(Ab + goffA[u], As[0] + (u * 256 + wb) * 8);
#pragma unroll
    for (int u = 0; u < 2; u++) glds16(Bb + goffB[u], Bs[0] + (u * 256 + wb) * 8);

#pragma unroll 1
    for (int kb = 0; kb < 16; kb++) {
        int cb = kb & 1;
        __syncthreads();                  // drains stage(kb) (issued one phase ago)
        if (kb < 15) {
            int k0n = (kb + 1) * 64;
#pragma unroll
            for (int u = 0; u < 4; u++)
                glds16(Ab + goffA[u] + k0n, As[cb ^ 1] + (u * 256 + wb) * 8);
#pragma unroll
            for (int u = 0; u < 2; u++)
                glds16(Bb + goffB[u] + k0n, Bs[cb ^ 1] + (u * 256 + wb) * 8);
        }
#pragma unroll
        for (int c = 0; c < 2; c++) {
            bf16x8 af[4], bfr[2];
#pragma unroll
            for (int i = 0; i < 4; i++) {
                int mt = wy * 4 + i;
                af[i] = *(bf16x8*)(As[cb] + ((mt * 2 + c) * 64 + lane) * 8);
            }
#pragma unroll
            for (int j = 0; j < 2; j++) {
                int nt = wx * 2 + j;
                bfr[j] = *(bf16x8*)(Bs[cb] + ((nt * 2 + c) * 64 + lane) * 8);
            }
#pragma unroll
            for (int i = 0; i < 4; i++)
#pragma unroll
                for (int j = 0; j < 2; j++)
                    acc[i][j] = __builtin_amdgcn_mfma_f32_16x16x32_bf16(af[i], bfr[j], acc[i][j], 0, 0, 0);
        }
    }
    int quad = lane >> 4, n16 = lane & 15;
#pragma unroll
    for (int i = 0; i < 4; i++) {
#pragma unroll
        for (int j = 0; j < 2; j++) {
            int col = bn * 64 + wx * 32 + j * 16 + n16;
#pragma unroll
            for (int r = 0; r < 4; r++) {
                int rowm = bm * 128 + wy * 64 + i * 16 + quad * 4 + r;
                if (CF32) ((float*)Cptr)[rowm * N + col] = acc[i][j][r];
                else      ((u16*)Cptr)[rowm * N + col] = f2bf(acc[i][j][r]);
            }
        }
    }
}

// ---------------- K_POST: fused [RMSNorm+RoPE in-place | v-LoRA+transpose] ---
#define NR_BLOCKS 20480
__global__ __launch_bounds__(256) void k_post(
    u16* __restrict__ qkv,
    const float* __restrict__ tq, const float* __restrict__ Bq,
    const float* __restrict__ gain,
    const float* __restrict__ tv, const float* __restrict__ Bv,
    const int* __restrict__ step_p, u16* __restrict__ vt)
{
    __shared__ __align__(16) u16 tile[64 * 64];
    int bx = blockIdx.x;
    int step = step_p[0];
    int valid = (step >= 0 && step < NSTEPS);
    int sc = valid ? step : 0;
    if (bx < NR_BLOCKS) {
        int wid = (bx * 256 + threadIdx.x) >> 6;
        int lane = threadIdx.x & 63;
        float val, postmul;
        u16* ptr;
        int s;
        if (wid < BATCH * NH * SEQ) {
            int b = wid >> 15;
            int h = (wid >> 11) & 15;
            s = wid & 2047;
            int row = b * SEQ + s;
            ptr = qkv + row * 1536 + h * HD + lane;
            val = bf2f(*ptr);
            const float* tr = tq + row * 4;
            float4 br = *(const float4*)(Bq + sc * DIM * RANK + (h * HD + lane) * RANK);
            val += tr[0] * br.x + tr[1] * br.y + tr[2] * br.z + tr[3] * br.w;
            postmul = gain[h] * 0.125f * 1.4426950408889634f;   // gain/sqrt(64)*log2e
        } else {
            int wk = wid - BATCH * NH * SEQ;
            int b = wk >> 13;
            int h = (wk >> 11) & 3;
            s = wk & 2047;
            int row = b * SEQ + s;
            ptr = qkv + row * 1536 + 1024 + h * HD + lane;
            val = bf2f(*ptr);
            postmul = 1.f;
        }
        float ss = val * val;
#pragma unroll
        for (int o = 32; o > 0; o >>= 1) ss += __shfl_xor(ss, o, 64);
        float rr = rsqrtf(ss * (1.f / 64.f) + 1.1920928955078125e-7f);
        float vn = val * rr;
        float partner = __shfl_xor(vn, 16, 64);
        float res;
        if (lane < 32) {
            int i = lane & 15;
            float invf = exp2f(-(float)i * 0.8304820237218405f);  // log2(10000)/16
            float ang = (float)s * invf;
            float cs = cosf(ang), sn = sinf(ang);
            res = (lane < 16) ? (vn * cs + partner * sn) : (-partner * sn + vn * cs);
        } else {
            res = vn;
        }
        *ptr = f2bf(res * postmul);
        return;
    }
    // ---- v transpose path ----
    int vb = bx - NR_BLOCKS;
    int st = vb & 31, g = (vb >> 5) & 3, b = vb >> 7;
    int t = threadIdx.x;
    int s_l = t & 63, dq = t >> 6;
    int row = b * SEQ + st * 64 + s_l;
    const float* tr = tv + row * 4;
    float t0 = tr[0], t1 = tr[1], t2 = tr[2], t3 = tr[3];
    const u16* src = qkv + row * 1536 + 1280 + g * HD + dq * 16;
#pragma unroll
    for (int e = 0; e < 16; e++) {
        int d = dq * 16 + e;
        float4 br = *(const float4*)(Bv + sc * (NKV * HD) * RANK + (g * HD + d) * RANK);
        float v = bf2f(src[e]) + t0 * br.x + t1 * br.y + t2 * br.z + t3 * br.w;
        tile[d * 64 + s_l] = f2bf(v);
    }
    __syncthreads();
#pragma unroll
    for (int u = 0; u < 2; u++) {
        int chunk = u * 256 + t;
        int d = chunk >> 3, scn = chunk & 7;
        *(uint4*)(vt + ((b * NKV + g) * HD + d) * SEQ + st * 64 + scn * 8) =
            *(uint4*)(tile + d * 64 + scn * 8);
    }
}

// ---------------- ATT: static-max flash attention, dbuf K/V staging ---------
// Block = (b,h,qt), longest-first. K/V tiles double-buffered in LDS: stage
// tile kt+1 right after the barrier so the barrier's vmcnt(0) drain covers
// loads issued a full compute-phase earlier (overlap, no stall).
__global__ __launch_bounds__(256) void k_attn(
    const u16* __restrict__ qkv, const u16* __restrict__ vt,
    const float* __restrict__ gain, u16* __restrict__ y)
{
    __shared__ __align__(16) u16 kf[2][4096];    // [img][64 keys][8 chunks^swz]
    __shared__ __align__(16) u16 vf[2][4096];    // [img][64 d][8 chunks^swz]
    __shared__ __align__(16) u16 pb[4][1024];    // per-wave P^T, B-frag linear
    int bx = blockIdx.x;
    int qt = 31 - (bx & 31);                     // longest blocks first
    int h = (bx >> 5) & 15, b = bx >> 9;
    int g = h >> 2;
    int t = threadIdx.x, lane = t & 63, w = t >> 6, wb = t & ~63;
    int quad = lane >> 4, n16 = lane & 15;
    int qrow = qt * 64 + w * 16 + n16;
    float negM = -11.67f * fabsf(gain[h]);       // static softmax max bound

    const u16* kbase = qkv + b * SEQ * 1536 + 1024 + g * HD;   // K rows stride 1536
    const u16* vbase = vt + (b * NKV + g) * HD * SEQ;          // V^T rows stride 2048
    const u16* qp = qkv + (b * SEQ + qrow) * 1536 + h * HD + quad * 8;
    bf16x8 qlo = *(const bf16x8*)qp;
    bf16x8 qhi = *(const bf16x8*)(qp + 32);

    // staging slot offsets: slot s holds row r=s>>3, global chunk c=(s&7)^(r&7)
    int koff[2], voff[2];
#pragma unroll
    for (int i = 0; i < 2; i++) {
        int s = i * 256 + t;
        int r = s >> 3, cc = s & 7;
        int c = cc ^ (r & 7);
        koff[i] = r * 1536 + c * 8;
        voff[i] = r * 2048 + c * 8;
    }
    // frag-read swizzled chunk offsets (16-B slots)
    int swb = n16 & 7;
    int o0 = n16 * 8 + (quad ^ swb);
    int o1 = n16 * 8 + ((4 + quad) ^ swb);
    u16* pw = pb[w];

    f32x4 acc[4];
#pragma unroll
    for (int i = 0; i < 4; i++) acc[i] = (f32x4){0.f, 0.f, 0.f, 0.f};
    float ps = 0.f;
    int ntiles = qt + 1;

    // stage tile 0 into image 0
    glds16(kbase + koff[0], kf[0] + wb * 8);
    glds16(kbase + koff[1], kf[0] + (256 + wb) * 8);
    glds16(vbase + voff[0], vf[0] + wb * 8);
    glds16(vbase + voff[1], vf[0] + (256 + wb) * 8);

#pragma unroll 1
    for (int kt = 0; kt < ntiles; kt++) {
        int cur = kt & 1;
        __syncthreads();                 // drains stage(kt); reads of img cur^1 done
        if (kt + 1 < ntiles) {           // prefetch tile kt+1 into the other image
            const u16* kp = kbase + (kt + 1) * 64 * 1536;
            const u16* vp = vbase + (kt + 1) * 64;
            u16* kd = kf[cur ^ 1];
            u16* vd = vf[cur ^ 1];
            glds16(kp + koff[0], kd + wb * 8);
            glds16(kp + koff[1], kd + (256 + wb) * 8);
            glds16(vp + voff[0], vd + wb * 8);
            glds16(vp + voff[1], vd + (256 + wb) * 8);
        }
        const u16* kc = kf[cur];
        const u16* vc = vf[cur];
        // S^T = K * Q^T : D[key][q]
        f32x4 st[4];
#pragma unroll
        for (int nt = 0; nt < 4; nt++) {
            f32x4 sa = (f32x4){0.f, 0.f, 0.f, 0.f};
            sa = __builtin_amdgcn_mfma_f32_16x16x32_bf16(*(bf16x8*)(kc + (nt * 128 + o0) * 8), qlo, sa, 0, 0, 0);
            sa = __builtin_amdgcn_mfma_f32_16x16x32_bf16(*(bf16x8*)(kc + (nt * 128 + o1) * 8), qhi, sa, 0, 0, 0);
            st[nt] = sa;
        }
        // p = exp2(s - M); causal zero on diagonal tile
        float p[4][4];
        if (kt == ntiles - 1) {
            int k0 = kt * 64;
#pragma unroll
            for (int nt = 0; nt < 4; nt++)
#pragma unroll
                for (int r = 0; r < 4; r++) {
                    int key = k0 + nt * 16 + quad * 4 + r;
                    float e = exp2f(st[nt][r] + negM);
                    e = (key > qrow) ? 0.f : e;
                    p[nt][r] = e;
                    ps += e;
                }
        } else {
#pragma unroll
            for (int nt = 0; nt < 4; nt++)
#pragma unroll
                for (int r = 0; r < 4; r++) {
                    float e = exp2f(st[nt][r] + negM);
                    p[nt][r] = e;
                    ps += e;
                }
        }
        // P^T -> per-wave LDS in B-frag linear layout
#pragma unroll
        for (int nt = 0; nt < 4; nt++) {
            u32 lo = pk2(p[nt][0], p[nt][1]);
            u32 hi = pk2(p[nt][2], p[nt][3]);
            int ck = nt >> 1;
            int qbk = (nt & 1) * 2 + (quad >> 1);
            int byteoff = (ck * 64 + qbk * 16 + n16) * 16 + (quad & 1) * 8;
            *(uint2*)((char*)pw + byteoff) = make_uint2(lo, hi);
        }
        asm volatile("s_waitcnt lgkmcnt(0)" ::: "memory");
        // Y^T += V^T * P^T
#pragma unroll
        for (int ck = 0; ck < 2; ck++) {
            bf16x8 pfr = *(bf16x8*)(pw + (ck * 64 + lane) * 8);
            int oo = ck ? o1 : o0;
#pragma unroll
            for (int dt = 0; dt < 4; dt++)
                acc[dt] = __builtin_amdgcn_mfma_f32_16x16x32_bf16(*(bf16x8*)(vc + (dt * 128 + oo) * 8), pfr, acc[dt], 0, 0, 0);
        }
        asm volatile("" ::: "memory");
    }
    // final l per q-col: in-lane ps + across the 4 quads holding this col
    ps += __shfl_xor(ps, 16, 64);
    ps += __shfl_xor(ps, 32, 64);
    float li = 1.f / ps;
#pragma unroll
    for (int dt = 0; dt < 4; dt++) {
        uint2 o = make_uint2(pk2(acc[dt][0] * li, acc[dt][1] * li),
                             pk2(acc[dt][2] * li, acc[dt][3] * li));
        int d = dt * 16 + quad * 4;
        *(uint2*)(y + (b * SEQ + qrow) * DIM + h * HD + d) = o;
    }
}

// ---------------------------------------------------------------------------
extern "C" void kernel_launch(void* const* d_in, const int* in_sizes, int n_in,
                              void* d_out, int out_size, void* d_ws, size_t ws_size,
                              hipStream_t stream)
{
    (void)in_sizes; (void)n_in; (void)out_size; (void)ws_size;
    const float* x     = (const float*)d_in[0];
    const float* Wq    = (const float*)d_in[1];
    const float* Wk    = (const float*)d_in[2];
    const float* Wv    = (const float*)d_in[3];
    const float* Wproj = (const float*)d_in[4];
    const float* qgain = (const float*)d_in[5];
    const float* Aq    = (const float*)d_in[6];
    const float* Bq    = (const float*)d_in[7];
    const float* Av    = (const float*)d_in[8];
    const float* Bv    = (const float*)d_in[9];
    const int*   step  = (const int*)d_in[10];

    // ws layout (25.1 MB): cvt [xb 8MB | Wqkv 3MB | Wproj 2MB] + qkv 12MB + tq/tv
    // reuse: y overlays xb; vt overlays Wqkv.
    char* ws = (char*)d_ws;
    u16* wsbf = (u16*)ws;
    u16* xb   = wsbf;
    u16* wf   = wsbf + XN;
    u16* wp   = wsbf + WV_END;
    u16* qkv  = (u16*)(ws + 13631488);
    float* tq = (float*)(ws + 26214400);
    float* tv = tq + 16384;
    u16* y    = xb;
    u16* vt   = wf;

    k_prep<<<CVT_BLOCKS + LORA_BLOCKS, 256, 0, stream>>>(x, Wq, Wk, Wv, Wproj, wsbf,
                                                         Aq, Av, step, tq, tv);
    k_gemm<false><<<768, 256, 0, stream>>>(xb, wf, qkv, 24, 1536);      // fused qkv
    k_post<<<NR_BLOCKS + 256, 256, 0, stream>>>(qkv, tq, Bq, qgain, tv, Bv, step, vt);
    k_attn<<<1024, 256, 0, stream>>>(qkv, vt, qgain, y);
    k_gemm<true><<<512, 256, 0, stream>>>(y, wp, d_out, 16, DIM);       // out proj
}

// Round 9
// 233.773 us; speedup vs baseline: 1.1158x; 1.0957x over previous
//
#include <hip/hip_runtime.h>
#include <hip/hip_bf16.h>
#include <stdint.h>

#define DIM 1024
#define NH 16
#define NKV 4
#define HD 64
#define SEQ 2048
#define BATCH 2
#define RANK 4
#define NSTEPS 2

// bf16 conversion-region element offsets (compile-time)
#define XN      4194304            // x: 4096*1024
#define WQ_END  5242880            // + 1024*1024
#define WK_END  5505024            // + 256*1024
#define WV_END  5767168            // + 256*1024
#define CVT_BLOCKS 6656
#define LORA_BLOCKS 1024

typedef unsigned short u16;
typedef unsigned int u32;
typedef __attribute__((ext_vector_type(8))) __bf16 bf16x8;
typedef __attribute__((ext_vector_type(4))) float f32x4;

__device__ __forceinline__ float bf2f(u16 v) {
    u32 u = ((u32)v) << 16;
    return __builtin_bit_cast(float, u);
}
__device__ __forceinline__ u16 f2bf(float f) {
    u32 u = __builtin_bit_cast(u32, f);
    u32 r = (u + 0x7fffu + ((u >> 16) & 1u)) >> 16;
    return (u16)r;
}
__device__ __forceinline__ u32 pk2(float a, float b) {
    return (u32)f2bf(a) | ((u32)f2bf(b) << 16);
}
// async global->LDS, 16 B per lane; lptr MUST be wave-uniform (HW adds lane*16)
__device__ __forceinline__ void glds16(const u16* g, u16* l) {
    __builtin_amdgcn_global_load_lds(
        (const __attribute__((address_space(1))) u32*)g,
        (__attribute__((address_space(3))) u32*)l, 16, 0, 0);
}

// ---------------- K_PREP: fused [fp32->bf16 convert | LoRA t = x@A^T] -------
__global__ __launch_bounds__(256) void k_prep(
    const float* __restrict__ x, const float* __restrict__ Wq,
    const float* __restrict__ Wk, const float* __restrict__ Wv,
    const float* __restrict__ Wp, u16* __restrict__ dst,
    const float* __restrict__ Aq, const float* __restrict__ Av,
    const int* __restrict__ step_p, float* __restrict__ tq, float* __restrict__ tv)
{
    int bx = blockIdx.x;
    if (bx < CVT_BLOCKS) {
        int e = (bx * 256 + threadIdx.x) * 4;
        const float* src;
        if (e < XN)          src = x  + e;
        else if (e < WQ_END) src = Wq + (e - XN);
        else if (e < WK_END) src = Wk + (e - WQ_END);
        else if (e < WV_END) src = Wv + (e - WK_END);
        else                 src = Wp + (e - WV_END);
        float4 v = *(const float4*)src;
        *(uint2*)(dst + e) = make_uint2(pk2(v.x, v.y), pk2(v.z, v.w));
        return;
    }
    int wave = ((bx - CVT_BLOCKS) * 256 + threadIdx.x) >> 6;
    int lane = threadIdx.x & 63;
    int step = step_p[0];
    int valid = (step >= 0 && step < NSTEPS);
    int sc = valid ? step : 0;
    const float* xr = x + wave * DIM + lane * 16;
    float xf[16];
#pragma unroll
    for (int q = 0; q < 4; q++) {
        float4 v4 = *(const float4*)(xr + q * 4);
        xf[q * 4 + 0] = v4.x; xf[q * 4 + 1] = v4.y;
        xf[q * 4 + 2] = v4.z; xf[q * 4 + 3] = v4.w;
    }
    float sums[8];
#pragma unroll
    for (int j = 0; j < 8; j++) {
        const float* ar = (j < 4 ? Aq + sc * RANK * DIM + j * DIM
                                 : Av + sc * RANK * DIM + (j - 4) * DIM) + lane * 16;
        float s = 0.f;
#pragma unroll
        for (int q = 0; q < 4; q++) {
            float4 a4 = *(const float4*)(ar + q * 4);
            s += xf[q * 4 + 0] * a4.x + xf[q * 4 + 1] * a4.y
               + xf[q * 4 + 2] * a4.z + xf[q * 4 + 3] * a4.w;
        }
#pragma unroll
        for (int o = 32; o > 0; o >>= 1) s += __shfl_xor(s, o, 64);
        sums[j] = s;
    }
    if (!valid) {
#pragma unroll
        for (int j = 0; j < 8; j++) sums[j] = 0.f;
    }
    if (lane == 0) {
        tq[wave * 4 + 0] = sums[0]; tq[wave * 4 + 1] = sums[1];
        tq[wave * 4 + 2] = sums[2]; tq[wave * 4 + 3] = sums[3];
        tv[wave * 4 + 0] = sums[4]; tv[wave * 4 + 1] = sums[5];
        tv[wave * 4 + 2] = sums[6]; tv[wave * 4 + 3] = sums[7];
    }
}

// ---------------- GEMM: 128x64 tile, BK=64, m97-style single-buffer + glds16
// (r7 version — best measured; dbuf regressed). C[M][N] = A[M][1024]*B[N][1024]^T.
template<bool CF32>
__global__ __launch_bounds__(256) void k_gemm(
    const u16* __restrict__ A, const u16* __restrict__ B,
    void* __restrict__ Cptr, int Ntiles, int N)
{
    __shared__ __align__(16) u16 As[8192];
    __shared__ __align__(16) u16 Bs[4096];
    int bx = blockIdx.x;
    int bn = bx % Ntiles, bm = bx / Ntiles;
    int t = threadIdx.x, lane = t & 63, w = t >> 6;
    int wy = w >> 1, wx = w & 1;
    int wb = t & ~63;                 // w*64, wave-uniform
    f32x4 acc[4][2];
#pragma unroll
    for (int i = 0; i < 4; i++)
#pragma unroll
        for (int j = 0; j < 2; j++) acc[i][j] = (f32x4){0.f, 0.f, 0.f, 0.f};

    int goffA[4], goffB[2];
#pragma unroll
    for (int u = 0; u < 4; u++) {
        int idx = u * 256 + t;
        int grp = idx >> 6;
        int quad = (idx >> 4) & 3, m = idx & 15;
        goffA[u] = ((grp >> 1) * 16 + m) * DIM + (grp & 1) * 32 + quad * 8;
    }
#pragma unroll
    for (int u = 0; u < 2; u++) {
        int idx = u * 256 + t;
        int grp = idx >> 6;
        int quad = (idx >> 4) & 3, m = idx & 15;
        goffB[u] = ((grp >> 1) * 16 + m) * DIM + (grp & 1) * 32 + quad * 8;
    }
    const u16* Ab = A + bm * 128 * DIM;
    const u16* Bb = B + bn * 64 * DIM;

#pragma unroll 1
    for (int kb = 0; kb < 16; kb++) {
        int k0 = kb * 64;
        __syncthreads();
#pragma unroll
        for (int u = 0; u < 4; u++)
            glds16(Ab + goffA[u] + k0, As + (u * 256 + wb) * 8);
#pragma unroll
        for (int u = 0; u < 2; u++)
            glds16(Bb + goffB[u] + k0, Bs + (u * 256 + wb) * 8);
        __syncthreads();
#pragma unroll
        for (int c = 0; c < 2; c++) {
            bf16x8 af[4], bfr[2];
#pragma unroll
            for (int i = 0; i < 4; i++) {
                int mt = wy * 4 + i;
                af[i] = *(bf16x8*)(As + ((mt * 2 + c) * 64 + lane) * 8);
            }
#pragma unroll
            for (int j = 0; j < 2; j++) {
                int nt = wx * 2 + j;
                bfr[j] = *(bf16x8*)(Bs + ((nt * 2 + c) * 64 + lane) * 8);
            }
#pragma unroll
            for (int i = 0; i < 4; i++)
#pragma unroll
                for (int j = 0; j < 2; j++)
                    acc[i][j] = __builtin_amdgcn_mfma_f32_16x16x32_bf16(af[i], bfr[j], acc[i][j], 0, 0, 0);
        }
    }
    int quad = lane >> 4, n16 = lane & 15;
#pragma unroll
    for (int i = 0; i < 4; i++) {
#pragma unroll
        for (int j = 0; j < 2; j++) {
            int col = bn * 64 + wx * 32 + j * 16 + n16;
#pragma unroll
            for (int r = 0; r < 4; r++) {
                int rowm = bm * 128 + wy * 64 + i * 16 + quad * 4 + r;
                if (CF32) ((float*)Cptr)[rowm * N + col] = acc[i][j][r];
                else      ((u16*)Cptr)[rowm * N + col] = f2bf(acc[i][j][r]);
            }
        }
    }
}

// ---------------- K_POST: fused [RMSNorm+RoPE in-place | v-LoRA+transpose] ---
#define NR_BLOCKS 20480
__global__ __launch_bounds__(256) void k_post(
    u16* __restrict__ qkv,
    const float* __restrict__ tq, const float* __restrict__ Bq,
    const float* __restrict__ gain,
    const float* __restrict__ tv, const float* __restrict__ Bv,
    const int* __restrict__ step_p, u16* __restrict__ vt)
{
    __shared__ __align__(16) u16 tile[64 * 64];
    int bx = blockIdx.x;
    int step = step_p[0];
    int valid = (step >= 0 && step < NSTEPS);
    int sc = valid ? step : 0;
    if (bx < NR_BLOCKS) {
        int wid = (bx * 256 + threadIdx.x) >> 6;
        int lane = threadIdx.x & 63;
        float val, postmul;
        u16* ptr;
        int s;
        if (wid < BATCH * NH * SEQ) {
            int b = wid >> 15;
            int h = (wid >> 11) & 15;
            s = wid & 2047;
            int row = b * SEQ + s;
            ptr = qkv + row * 1536 + h * HD + lane;
            val = bf2f(*ptr);
            const float* tr = tq + row * 4;
            float4 br = *(const float4*)(Bq + sc * DIM * RANK + (h * HD + lane) * RANK);
            val += tr[0] * br.x + tr[1] * br.y + tr[2] * br.z + tr[3] * br.w;
            postmul = gain[h] * 0.125f * 1.4426950408889634f;   // gain/sqrt(64)*log2e
        } else {
            int wk = wid - BATCH * NH * SEQ;
            int b = wk >> 13;
            int h = (wk >> 11) & 3;
            s = wk & 2047;
            int row = b * SEQ + s;
            ptr = qkv + row * 1536 + 1024 + h * HD + lane;
            val = bf2f(*ptr);
            postmul = 1.f;
        }
        float ss = val * val;
#pragma unroll
        for (int o = 32; o > 0; o >>= 1) ss += __shfl_xor(ss, o, 64);
        float rr = rsqrtf(ss * (1.f / 64.f) + 1.1920928955078125e-7f);
        float vn = val * rr;
        float partner = __shfl_xor(vn, 16, 64);
        float res;
        if (lane < 32) {
            int i = lane & 15;
            float invf = exp2f(-(float)i * 0.8304820237218405f);  // log2(10000)/16
            float ang = (float)s * invf;
            float cs = cosf(ang), sn = sinf(ang);
            res = (lane < 16) ? (vn * cs + partner * sn) : (-partner * sn + vn * cs);
        } else {
            res = vn;
        }
        *ptr = f2bf(res * postmul);
        return;
    }
    // ---- v transpose path ----
    int vb = bx - NR_BLOCKS;
    int st = vb & 31, g = (vb >> 5) & 3, b = vb >> 7;
    int t = threadIdx.x;
    int s_l = t & 63, dq = t >> 6;
    int row = b * SEQ + st * 64 + s_l;
    const float* tr = tv + row * 4;
    float t0 = tr[0], t1 = tr[1], t2 = tr[2], t3 = tr[3];
    const u16* src = qkv + row * 1536 + 1280 + g * HD + dq * 16;
#pragma unroll
    for (int e = 0; e < 16; e++) {
        int d = dq * 16 + e;
        float4 br = *(const float4*)(Bv + sc * (NKV * HD) * RANK + (g * HD + d) * RANK);
        float v = bf2f(src[e]) + t0 * br.x + t1 * br.y + t2 * br.z + t3 * br.w;
        tile[d * 64 + s_l] = f2bf(v);
    }
    __syncthreads();
#pragma unroll
    for (int u = 0; u < 2; u++) {
        int chunk = u * 256 + t;
        int d = chunk >> 3, scn = chunk & 7;
        *(uint4*)(vt + ((b * NKV + g) * HD + d) * SEQ + st * 64 + scn * 8) =
            *(uint4*)(tile + d * 64 + scn * 8);
    }
}

// ---------------- ATT: static-max flash attention, UNIFORM split blocks -----
// pairsel=(b,h,qtsel 0..15). Block A (role 0, 17 iters): all of q-tile qtsel
// (writes y) + first 16-qtsel key-tiles of q-tile 31-qtsel (partial). Block B
// (role 1, 16 iters): remaining 16 key-tiles of q-tile 31-qtsel (partial).
// Static-max => partials (acc, ps) over disjoint key ranges ADD; k_comb merges.
__global__ __launch_bounds__(256) void k_attn(
    const u16* __restrict__ qkv, const u16* __restrict__ vt,
    const float* __restrict__ gain, u16* __restrict__ y,
    float* __restrict__ accP, float* __restrict__ psP)
{
    __shared__ __align__(16) u16 kf[4096];       // [64 keys][8 chunks^swz]
    __shared__ __align__(16) u16 vf[4096];       // [64 d][8 chunks^swz]
    __shared__ __align__(16) u16 pb[4][1024];    // per-wave P^T, B-frag linear
    int bx = blockIdx.x;
    int pairsel = bx >> 1, role = bx & 1;
    int b = pairsel >> 8, h = (pairsel >> 4) & 15, qtsel = pairsel & 15;
    int g = h >> 2;
    int t = threadIdx.x, lane = t & 63, w = t >> 6, wb = t & ~63;
    int quad = lane >> 4, n16 = lane & 15;
    float negM = -11.67f * fabsf(gain[h]);       // static softmax max bound

    const u16* kbase = qkv + b * SEQ * 1536 + 1024 + g * HD;   // K rows stride 1536
    const u16* vbase = vt + (b * NKV + g) * HD * SEQ;          // V^T rows stride 2048

    // staging slot offsets: slot s holds row r=s>>3, global chunk c=(s&7)^(r&7)
    int koff0, koff1, voff0, voff1;
    {
        int s0 = t, r0 = s0 >> 3, c0 = (s0 & 7) ^ (r0 & 7);
        koff0 = r0 * 1536 + c0 * 8;  voff0 = r0 * 2048 + c0 * 8;
        int s1 = 256 + t, r1 = s1 >> 3, c1 = (s1 & 7) ^ (r1 & 7);
        koff1 = r1 * 1536 + c1 * 8;  voff1 = r1 * 2048 + c1 * 8;
    }
    // frag-read swizzled chunk offsets (16-B slots)
    int swb = n16 & 7;
    int o0 = n16 * 8 + (quad ^ swb);
    int o1 = n16 * 8 + ((4 + quad) ^ swb);
    u16* pw = pb[w];

    f32x4 acc[4];
    float ps;
    bf16x8 qlo, qhi;
    int qrow;

    auto reset_acc = [&]() {
#pragma unroll
        for (int i = 0; i < 4; i++) acc[i] = (f32x4){0.f, 0.f, 0.f, 0.f};
        ps = 0.f;
    };
    auto load_q = [&](int qt) {
        qrow = qt * 64 + w * 16 + n16;
        const u16* qp = qkv + (b * SEQ + qrow) * 1536 + h * HD + quad * 8;
        qlo = *(const bf16x8*)qp;
        qhi = *(const bf16x8*)(qp + 32);
    };
    auto tile = [&](int kt) {
        __syncthreads();                          // prior tile's LDS reads done
        const u16* kp = kbase + kt * (64 * 1536);
        const u16* vp = vbase + kt * 64;
        glds16(kp + koff0, kf + wb * 8);
        glds16(kp + koff1, kf + (256 + wb) * 8);
        glds16(vp + voff0, vf + wb * 8);
        glds16(vp + voff1, vf + (256 + wb) * 8);
        __syncthreads();                          // vmcnt drained at barrier
        f32x4 st[4];
#pragma unroll
        for (int nt = 0; nt < 4; nt++) {
            f32x4 sa = (f32x4){0.f, 0.f, 0.f, 0.f};
            sa = __builtin_amdgcn_mfma_f32_16x16x32_bf16(*(bf16x8*)(kf + (nt * 128 + o0) * 8), qlo, sa, 0, 0, 0);
            sa = __builtin_amdgcn_mfma_f32_16x16x32_bf16(*(bf16x8*)(kf + (nt * 128 + o1) * 8), qhi, sa, 0, 0, 0);
            st[nt] = sa;
        }
        float p[4][4];
        int kb0 = kt * 64;
#pragma unroll
        for (int nt = 0; nt < 4; nt++)
#pragma unroll
            for (int r = 0; r < 4; r++) {
                int key = kb0 + nt * 16 + quad * 4 + r;
                float e = exp2f(st[nt][r] + negM);
                e = (key > qrow) ? 0.f : e;       // no-op off-diagonal
                p[nt][r] = e;
                ps += e;
            }
#pragma unroll
        for (int nt = 0; nt < 4; nt++) {
            u32 lo = pk2(p[nt][0], p[nt][1]);
            u32 hi = pk2(p[nt][2], p[nt][3]);
            int ck = nt >> 1;
            int qbk = (nt & 1) * 2 + (quad >> 1);
            int byteoff = (ck * 64 + qbk * 16 + n16) * 16 + (quad & 1) * 8;
            *(uint2*)((char*)pw + byteoff) = make_uint2(lo, hi);
        }
        asm volatile("s_waitcnt lgkmcnt(0)" ::: "memory");
#pragma unroll
        for (int ck = 0; ck < 2; ck++) {
            bf16x8 pfr = *(bf16x8*)(pw + (ck * 64 + lane) * 8);
            int oo = ck ? o1 : o0;
#pragma unroll
            for (int dt = 0; dt < 4; dt++)
                acc[dt] = __builtin_amdgcn_mfma_f32_16x16x32_bf16(*(bf16x8*)(vf + (dt * 128 + oo) * 8), pfr, acc[dt], 0, 0, 0);
        }
        asm volatile("" ::: "memory");
    };
    auto write_partial = [&](int pidx) {
        float pt = ps + __shfl_xor(ps, 16, 64);
        pt += __shfl_xor(pt, 32, 64);
        if (quad == 0) psP[pidx * 64 + w * 16 + n16] = pt;
        float* ap = accP + pidx * 4096 + w * 1024;
#pragma unroll
        for (int dt = 0; dt < 4; dt++)
#pragma unroll
            for (int r = 0; r < 4; r++)
                ap[dt * 256 + quad * 64 + r * 16 + n16] = acc[dt][r];
    };

    if (role == 0) {
        // phase 1: q-tile qtsel, full causal range -> y direct
        load_q(qtsel);
        reset_acc();
#pragma unroll 1
        for (int kt = 0; kt <= qtsel; kt++) tile(kt);
        {
            float pt = ps + __shfl_xor(ps, 16, 64);
            pt += __shfl_xor(pt, 32, 64);
            float li = 1.f / pt;
#pragma unroll
            for (int dt = 0; dt < 4; dt++) {
                uint2 o = make_uint2(pk2(acc[dt][0] * li, acc[dt][1] * li),
                                     pk2(acc[dt][2] * li, acc[dt][3] * li));
                int d = dt * 16 + quad * 4;
                *(uint2*)(y + (b * SEQ + qrow) * DIM + h * HD + d) = o;
            }
        }
        // phase 2: q-tile 31-qtsel, key-tiles 0..15-qtsel -> partial
        load_q(31 - qtsel);
        reset_acc();
#pragma unroll 1
        for (int kt = 0; kt <= 15 - qtsel; kt++) tile(kt);
        write_partial(pairsel * 2);
    } else {
        // q-tile 31-qtsel, key-tiles 16-qtsel..31-qtsel (incl diagonal) -> partial
        load_q(31 - qtsel);
        reset_acc();
#pragma unroll 1
        for (int kt = 16 - qtsel; kt <= 31 - qtsel; kt++) tile(kt);
        write_partial(pairsel * 2 + 1);
    }
}

// ---------------- K_COMB: merge split-K partials for high q-tiles ----------
__global__ __launch_bounds__(256) void k_comb(
    const float* __restrict__ accP, const float* __restrict__ psP,
    u16* __restrict__ y)
{
    int pairsel = blockIdx.x;
    int b = pairsel >> 8, h = (pairsel >> 4) & 15, qtsel = pairsel & 15;
    int qt = 31 - qtsel;
    int t = threadIdx.x, w = t >> 6, d = t & 63;
    const float* a0 = accP + (pairsel * 2) * 4096 + t * 16;
    const float* a1 = a0 + 4096;
    const float* p0 = psP + pairsel * 128 + w * 16;
    const float* p1 = p0 + 64;
    u16* yp = y + (b * SEQ + qt * 64 + w * 16) * DIM + h * HD + d;
#pragma unroll
    for (int i = 0; i < 4; i++) {
        float4 v0 = *(const float4*)(a0 + i * 4);
        float4 v1 = *(const float4*)(a1 + i * 4);
        float4 s0 = *(const float4*)(p0 + i * 4);
        float4 s1 = *(const float4*)(p1 + i * 4);
        yp[(i * 4 + 0) * DIM] = f2bf((v0.x + v1.x) / (s0.x + s1.x));
        yp[(i * 4 + 1) * DIM] = f2bf((v0.y + v1.y) / (s0.y + s1.y));
        yp[(i * 4 + 2) * DIM] = f2bf((v0.z + v1.z) / (s0.z + s1.z));
        yp[(i * 4 + 3) * DIM] = f2bf((v0.w + v1.w) / (s0.w + s1.w));
    }
}

// ---------------------------------------------------------------------------
extern "C" void kernel_launch(void* const* d_in, const int* in_sizes, int n_in,
                              void* d_out, int out_size, void* d_ws, size_t ws_size,
                              hipStream_t stream)
{
    (void)in_sizes; (void)n_in; (void)out_size; (void)ws_size;
    const float* x     = (const float*)d_in[0];
    const float* Wq    = (const float*)d_in[1];
    const float* Wk    = (const float*)d_in[2];
    const float* Wv    = (const float*)d_in[3];
    const float* Wproj = (const float*)d_in[4];
    const float* qgain = (const float*)d_in[5];
    const float* Aq    = (const float*)d_in[6];
    const float* Bq    = (const float*)d_in[7];
    const float* Av    = (const float*)d_in[8];
    const float* Bv    = (const float*)d_in[9];
    const int*   step  = (const int*)d_in[10];

    // ws layout (26.6 MB): cvt [xb 8MB | Wqkv 3MB | Wproj 2MB] + qkv 12MB +
    // tq/tv (128KB) + psP (256KB). accP (16MB fp32) lives in d_out (dead until
    // final proj GEMM overwrites it). reuse: y overlays xb; vt overlays Wqkv.
    char* ws = (char*)d_ws;
    u16* wsbf = (u16*)ws;
    u16* xb   = wsbf;
    u16* wf   = wsbf + XN;
    u16* wp   = wsbf + WV_END;
    u16* qkv  = (u16*)(ws + 13631488);
    float* tq = (float*)(ws + 26214400);
    float* tv = tq + 16384;
    float* psP = (float*)(ws + 26345472);
    float* accP = (float*)d_out;
    u16* y    = xb;
    u16* vt   = wf;

    k_prep<<<CVT_BLOCKS + LORA_BLOCKS, 256, 0, stream>>>(x, Wq, Wk, Wv, Wproj, wsbf,
                                                         Aq, Av, step, tq, tv);
    k_gemm<false><<<768, 256, 0, stream>>>(xb, wf, qkv, 24, 1536);      // fused qkv
    k_post<<<NR_BLOCKS + 256, 256, 0, stream>>>(qkv, tq, Bq, qgain, tv, Bv, step, vt);
    k_attn<<<1024, 256, 0, stream>>>(qkv, vt, qgain, y, accP, psP);
    k_comb<<<512, 256, 0, stream>>>(accP, psP, y);
    k_gemm<true><<<512, 256, 0, stream>>>(y, wp, d_out, 16, DIM);       // out proj
}

// Round 10
// 216.942 us; speedup vs baseline: 1.2024x; 1.0776x over previous
//
#include <hip/hip_runtime.h>
#include <hip/hip_bf16.h>
#include <stdint.h>

#define DIM 1024
#define NH 16
#define NKV 4
#define HD 64
#define SEQ 2048
#define BATCH 2
#define RANK 4
#define NSTEPS 2

// bf16 conversion-region element offsets (compile-time)
#define XN      4194304            // x: 4096*1024
#define WQ_END  5242880            // + 1024*1024
#define WK_END  5505024            // + 256*1024
#define WV_END  5767168            // + 256*1024
#define CVT_BLOCKS 6656
#define LORA_BLOCKS 1024

typedef unsigned short u16;
typedef unsigned int u32;
typedef __attribute__((ext_vector_type(8))) __bf16 bf16x8;
typedef __attribute__((ext_vector_type(4))) float f32x4;

__device__ __forceinline__ float bf2f(u16 v) {
    u32 u = ((u32)v) << 16;
    return __builtin_bit_cast(float, u);
}
__device__ __forceinline__ u16 f2bf(float f) {
    u32 u = __builtin_bit_cast(u32, f);
    u32 r = (u + 0x7fffu + ((u >> 16) & 1u)) >> 16;
    return (u16)r;
}
__device__ __forceinline__ u32 pk2(float a, float b) {
    return (u32)f2bf(a) | ((u32)f2bf(b) << 16);
}
// truncation-pack two fp32->bf16 in ONE v_perm_b32 (bias cancels in softmax)
__device__ __forceinline__ u32 pk2t(float a, float b) {
    return __builtin_amdgcn_perm(__builtin_bit_cast(u32, b),
                                 __builtin_bit_cast(u32, a), 0x07060302u);
}
// async global->LDS, 16 B per lane; lptr MUST be wave-uniform (HW adds lane*16)
__device__ __forceinline__ void glds16(const u16* g, u16* l) {
    __builtin_amdgcn_global_load_lds(
        (const __attribute__((address_space(1))) u32*)g,
        (__attribute__((address_space(3))) u32*)l, 16, 0, 0);
}

// ---------------- K_PREP: fused [fp32->bf16 convert | LoRA t = x@A^T] -------
__global__ __launch_bounds__(256) void k_prep(
    const float* __restrict__ x, const float* __restrict__ Wq,
    const float* __restrict__ Wk, const float* __restrict__ Wv,
    const float* __restrict__ Wp, u16* __restrict__ dst,
    const float* __restrict__ Aq, const float* __restrict__ Av,
    const int* __restrict__ step_p, float* __restrict__ tq, float* __restrict__ tv)
{
    int bx = blockIdx.x;
    if (bx < CVT_BLOCKS) {
        int e = (bx * 256 + threadIdx.x) * 4;
        const float* src;
        if (e < XN)          src = x  + e;
        else if (e < WQ_END) src = Wq + (e - XN);
        else if (e < WK_END) src = Wk + (e - WQ_END);
        else if (e < WV_END) src = Wv + (e - WK_END);
        else                 src = Wp + (e - WV_END);
        float4 v = *(const float4*)src;
        *(uint2*)(dst + e) = make_uint2(pk2(v.x, v.y), pk2(v.z, v.w));
        return;
    }
    int wave = ((bx - CVT_BLOCKS) * 256 + threadIdx.x) >> 6;
    int lane = threadIdx.x & 63;
    int step = step_p[0];
    int valid = (step >= 0 && step < NSTEPS);
    int sc = valid ? step : 0;
    const float* xr = x + wave * DIM + lane * 16;
    float xf[16];
#pragma unroll
    for (int q = 0; q < 4; q++) {
        float4 v4 = *(const float4*)(xr + q * 4);
        xf[q * 4 + 0] = v4.x; xf[q * 4 + 1] = v4.y;
        xf[q * 4 + 2] = v4.z; xf[q * 4 + 3] = v4.w;
    }
    float sums[8];
#pragma unroll
    for (int j = 0; j < 8; j++) {
        const float* ar = (j < 4 ? Aq + sc * RANK * DIM + j * DIM
                                 : Av + sc * RANK * DIM + (j - 4) * DIM) + lane * 16;
        float s = 0.f;
#pragma unroll
        for (int q = 0; q < 4; q++) {
            float4 a4 = *(const float4*)(ar + q * 4);
            s += xf[q * 4 + 0] * a4.x + xf[q * 4 + 1] * a4.y
               + xf[q * 4 + 2] * a4.z + xf[q * 4 + 3] * a4.w;
        }
#pragma unroll
        for (int o = 32; o > 0; o >>= 1) s += __shfl_xor(s, o, 64);
        sums[j] = s;
    }
    if (!valid) {
#pragma unroll
        for (int j = 0; j < 8; j++) sums[j] = 0.f;
    }
    if (lane == 0) {
        tq[wave * 4 + 0] = sums[0]; tq[wave * 4 + 1] = sums[1];
        tq[wave * 4 + 2] = sums[2]; tq[wave * 4 + 3] = sums[3];
        tv[wave * 4 + 0] = sums[4]; tv[wave * 4 + 1] = sums[5];
        tv[wave * 4 + 2] = sums[6]; tv[wave * 4 + 3] = sums[7];
    }
}

// ---------------- QKV GEMM + fused post (LoRA/RMS/RoPE/gain/vtrans) ---------
// 128x64 tile, BK=64, single-buffer glds16 (r7 structure, best measured).
// XCD swizzle: bn grouped per XCD -> W tiles L2-resident (384 KB/XCD).
// bn 0..15: q-head h=bn (LoRA+RMS+RoPE+gain); 16..19: k-head (RMS+RoPE);
// 20..23: v (LoRA, write transposed to vt). N-tile 64 == one head.
__global__ __launch_bounds__(256) void k_gemm_qkv(
    const u16* __restrict__ A, const u16* __restrict__ B,
    u16* __restrict__ qkv, u16* __restrict__ vtb,
    const float* __restrict__ tq, const float* __restrict__ Bq,
    const float* __restrict__ tv, const float* __restrict__ Bv,
    const float* __restrict__ gain, const int* __restrict__ step_p)
{
    __shared__ __align__(16) u16 As[8192];
    __shared__ __align__(16) u16 Bs[4096];
    __shared__ float sred[2][2][64];
    int bx = blockIdx.x;
    int bn = (bx & 7) * 3 + ((bx >> 3) % 3);     // XCD-resident weight tile
    int bm = (bx >> 3) / 3;
    int t = threadIdx.x, lane = t & 63, w = t >> 6;
    int wy = w >> 1, wx = w & 1;
    int wb = t & ~63;
    int quad = lane >> 4, n16 = lane & 15;
    f32x4 acc[4][2];
#pragma unroll
    for (int i = 0; i < 4; i++)
#pragma unroll
        for (int j = 0; j < 2; j++) acc[i][j] = (f32x4){0.f, 0.f, 0.f, 0.f};

    int goffA[4], goffB[2];
#pragma unroll
    for (int u = 0; u < 4; u++) {
        int idx = u * 256 + t;
        int grp = idx >> 6;
        int q_ = (idx >> 4) & 3, m = idx & 15;
        goffA[u] = ((grp >> 1) * 16 + m) * DIM + (grp & 1) * 32 + q_ * 8;
    }
#pragma unroll
    for (int u = 0; u < 2; u++) {
        int idx = u * 256 + t;
        int grp = idx >> 6;
        int q_ = (idx >> 4) & 3, m = idx & 15;
        goffB[u] = ((grp >> 1) * 16 + m) * DIM + (grp & 1) * 32 + q_ * 8;
    }
    const u16* Ab = A + bm * 128 * DIM;
    const u16* Bb = B + bn * 64 * DIM;

#pragma unroll 1
    for (int kb = 0; kb < 16; kb++) {
        int k0 = kb * 64;
        __syncthreads();
#pragma unroll
        for (int u = 0; u < 4; u++)
            glds16(Ab + goffA[u] + k0, As + (u * 256 + wb) * 8);
#pragma unroll
        for (int u = 0; u < 2; u++)
            glds16(Bb + goffB[u] + k0, Bs + (u * 256 + wb) * 8);
        __syncthreads();
#pragma unroll
        for (int c = 0; c < 2; c++) {
            bf16x8 af[4], bfr[2];
#pragma unroll
            for (int i = 0; i < 4; i++)
                af[i] = *(bf16x8*)(As + (((wy * 4 + i) * 2 + c) * 64 + lane) * 8);
#pragma unroll
            for (int j = 0; j < 2; j++)
                bfr[j] = *(bf16x8*)(Bs + (((wx * 2 + j) * 2 + c) * 64 + lane) * 8);
#pragma unroll
            for (int i = 0; i < 4; i++)
#pragma unroll
                for (int j = 0; j < 2; j++)
                    acc[i][j] = __builtin_amdgcn_mfma_f32_16x16x32_bf16(af[i], bfr[j], acc[i][j], 0, 0, 0);
        }
    }

    // ---------------- fused epilogue ----------------
    int step = step_p[0];
    int sc = (step >= 0 && step < NSTEPS) ? step : 0;
    int col_l0 = wx * 32 + n16;                  // j=0 col within head
    int row_base = bm * 128 + wy * 64 + quad * 4;

    if (bn < 20) {
        bool isq = (bn < 16);
        // LoRA add for q (tq zeroed when step invalid)
        if (isq) {
            float4 B40 = *(const float4*)(Bq + (sc * DIM + bn * 64 + col_l0) * RANK);
            float4 B41 = *(const float4*)(Bq + (sc * DIM + bn * 64 + col_l0 + 16) * RANK);
#pragma unroll
            for (int i = 0; i < 4; i++)
#pragma unroll
                for (int r = 0; r < 4; r++) {
                    float4 t4 = *(const float4*)(tq + (row_base + i * 16 + r) * 4);
                    acc[i][0][r] += t4.x * B40.x + t4.y * B40.y + t4.z * B40.z + t4.w * B40.w;
                    acc[i][1][r] += t4.x * B41.x + t4.y * B41.y + t4.z * B41.z + t4.w * B41.w;
                }
        }
        // per-row sum of squares over this wave's 32 cols, reduce over n16
        float sq[4][4];
#pragma unroll
        for (int i = 0; i < 4; i++)
#pragma unroll
            for (int r = 0; r < 4; r++) {
                float s = acc[i][0][r] * acc[i][0][r] + acc[i][1][r] * acc[i][1][r];
#pragma unroll
                for (int o = 1; o < 16; o <<= 1) s += __shfl_xor(s, o, 64);
                sq[i][r] = s;
            }
        if (n16 == 0) {
#pragma unroll
            for (int i = 0; i < 4; i++)
#pragma unroll
                for (int r = 0; r < 4; r++)
                    sred[wy][wx][i * 16 + quad * 4 + r] = sq[i][r];
        }
        __syncthreads();
        float postmul = isq ? (gain[bn] * 0.125f * 1.4426950408889634f) : 1.f;
        int colbase = isq ? (bn * 64) : (1024 + (bn - 16) * 64);
        float invf = exp2f(-(float)n16 * 0.8304820237218405f);  // log2(10000)/16
#pragma unroll
        for (int i = 0; i < 4; i++)
#pragma unroll
            for (int r = 0; r < 4; r++) {
                int rl = i * 16 + quad * 4 + r;
                float total = sq[i][r] + sred[wy][wx ^ 1][rl];
                float rr = rsqrtf(total * (1.f / 64.f) + 1.1920928955078125e-7f);
                int row = bm * 128 + wy * 64 + rl;
                float v0 = acc[i][0][r] * rr, v1 = acc[i][1][r] * rr;
                float o0, o1;
                if (wx == 0) {   // cols 0..31: RoPE rotate (pair j0<->j1, in-lane)
                    float ang = (float)(row & 2047) * invf;
                    float cs = cosf(ang), sn = sinf(ang);
                    o0 = v0 * cs + v1 * sn;
                    o1 = -v0 * sn + v1 * cs;
                } else {
                    o0 = v0; o1 = v1;
                }
                u16* dst = qkv + row * 1536 + colbase + col_l0;
                dst[0]  = f2bf(o0 * postmul);
                dst[16] = f2bf(o1 * postmul);
            }
    } else {
        // V: LoRA add then transposed write to vt[b][g][d][s]
        int g = bn - 20;
        float4 B40 = *(const float4*)(Bv + (sc * (NKV * HD) + g * 64 + col_l0) * RANK);
        float4 B41 = *(const float4*)(Bv + (sc * (NKV * HD) + g * 64 + col_l0 + 16) * RANK);
#pragma unroll
        for (int i = 0; i < 4; i++) {
#pragma unroll
            for (int r = 0; r < 4; r++) {
                float4 t4 = *(const float4*)(tv + (row_base + i * 16 + r) * 4);
                acc[i][0][r] += t4.x * B40.x + t4.y * B40.y + t4.z * B40.z + t4.w * B40.w;
                acc[i][1][r] += t4.x * B41.x + t4.y * B41.y + t4.z * B41.z + t4.w * B41.w;
            }
            int row0 = row_base + i * 16;          // 4 consecutive rows r=0..3
            int b = row0 >> 11, s0 = row0 & 2047;
#pragma unroll
            for (int j = 0; j < 2; j++) {
                int d = col_l0 + j * 16;
                uint2 pkv = make_uint2(pk2(acc[i][j][0], acc[i][j][1]),
                                       pk2(acc[i][j][2], acc[i][j][3]));
                *(uint2*)(vtb + ((b * NKV + g) * HD + d) * SEQ + s0) = pkv;
            }
        }
    }
}

// ---------------- PROJ GEMM: 128x64 tile, fp32 C, XCD swizzle ---------------
__global__ __launch_bounds__(256) void k_gemm_proj(
    const u16* __restrict__ A, const u16* __restrict__ B,
    float* __restrict__ C)
{
    __shared__ __align__(16) u16 As[8192];
    __shared__ __align__(16) u16 Bs[4096];
    int bx = blockIdx.x;
    int bn = (bx & 7) * 2 + ((bx >> 3) & 1);
    int bm = bx >> 4;
    int t = threadIdx.x, lane = t & 63, w = t >> 6;
    int wy = w >> 1, wx = w & 1;
    int wb = t & ~63;
    f32x4 acc[4][2];
#pragma unroll
    for (int i = 0; i < 4; i++)
#pragma unroll
        for (int j = 0; j < 2; j++) acc[i][j] = (f32x4){0.f, 0.f, 0.f, 0.f};

    int goffA[4], goffB[2];
#pragma unroll
    for (int u = 0; u < 4; u++) {
        int idx = u * 256 + t;
        int grp = idx >> 6;
        int q_ = (idx >> 4) & 3, m = idx & 15;
        goffA[u] = ((grp >> 1) * 16 + m) * DIM + (grp & 1) * 32 + q_ * 8;
    }
#pragma unroll
    for (int u = 0; u < 2; u++) {
        int idx = u * 256 + t;
        int grp = idx >> 6;
        int q_ = (idx >> 4) & 3, m = idx & 15;
        goffB[u] = ((grp >> 1) * 16 + m) * DIM + (grp & 1) * 32 + q_ * 8;
    }
    const u16* Ab = A + bm * 128 * DIM;
    const u16* Bb = B + bn * 64 * DIM;

#pragma unroll 1
    for (int kb = 0; kb < 16; kb++) {
        int k0 = kb * 64;
        __syncthreads();
#pragma unroll
        for (int u = 0; u < 4; u++)
            glds16(Ab + goffA[u] + k0, As + (u * 256 + wb) * 8);
#pragma unroll
        for (int u = 0; u < 2; u++)
            glds16(Bb + goffB[u] + k0, Bs + (u * 256 + wb) * 8);
        __syncthreads();
#pragma unroll
        for (int c = 0; c < 2; c++) {
            bf16x8 af[4], bfr[2];
#pragma unroll
            for (int i = 0; i < 4; i++)
                af[i] = *(bf16x8*)(As + (((wy * 4 + i) * 2 + c) * 64 + lane) * 8);
#pragma unroll
            for (int j = 0; j < 2; j++)
                bfr[j] = *(bf16x8*)(Bs + (((wx * 2 + j) * 2 + c) * 64 + lane) * 8);
#pragma unroll
            for (int i = 0; i < 4; i++)
#pragma unroll
                for (int j = 0; j < 2; j++)
                    acc[i][j] = __builtin_amdgcn_mfma_f32_16x16x32_bf16(af[i], bfr[j], acc[i][j], 0, 0, 0);
        }
    }
    int quad = lane >> 4, n16 = lane & 15;
#pragma unroll
    for (int i = 0; i < 4; i++)
#pragma unroll
        for (int j = 0; j < 2; j++) {
            int col = bn * 64 + wx * 32 + j * 16 + n16;
#pragma unroll
            for (int r = 0; r < 4; r++) {
                int rowm = bm * 128 + wy * 64 + i * 16 + quad * 4 + r;
                C[rowm * DIM + col] = acc[i][j][r];
            }
        }
}

// ---------------- ATT: static-max split-K flash attention, XCD-grouped ------
// XCD = bx&7 = (b,g): all 128 blocks sharing K/V land on one XCD (L2-resident).
// Block roles as r9: role 0 = q-tile qtsel full (y) + low half of 31-qtsel
// (partial); role 1 = high half of 31-qtsel (partial). Uniform 16-17 iters.
__global__ __launch_bounds__(256) void k_attn(
    const u16* __restrict__ qkv, const u16* __restrict__ vt,
    const float* __restrict__ gain, u16* __restrict__ y,
    float* __restrict__ accP, float* __restrict__ psP)
{
    __shared__ __align__(16) u16 kf[4096];
    __shared__ __align__(16) u16 vf[4096];
    __shared__ __align__(16) u16 pb[4][1024];
    int bx = blockIdx.x;
    int bgid = bx & 7, inner = bx >> 3;
    int b = bgid >> 2, g = bgid & 3;
    int h = g * 4 + (inner & 3);
    int qtsel = (inner >> 2) & 15;
    int role = (inner >> 6) & 1;
    int pairsel = (b * 16 + h) * 16 + qtsel;
    int t = threadIdx.x, lane = t & 63, w = t >> 6, wb = t & ~63;
    int quad = lane >> 4, n16 = lane & 15;
    float negM = -11.67f * fabsf(gain[h]);

    const u16* kbase = qkv + b * SEQ * 1536 + 1024 + g * HD;
    const u16* vbase = vt + (b * NKV + g) * HD * SEQ;

    int koff0, koff1, voff0, voff1;
    {
        int s0 = t, r0 = s0 >> 3, c0 = (s0 & 7) ^ (r0 & 7);
        koff0 = r0 * 1536 + c0 * 8;  voff0 = r0 * 2048 + c0 * 8;
        int s1 = 256 + t, r1 = s1 >> 3, c1 = (s1 & 7) ^ (r1 & 7);
        koff1 = r1 * 1536 + c1 * 8;  voff1 = r1 * 2048 + c1 * 8;
    }
    int swb = n16 & 7;
    int o0 = n16 * 8 + (quad ^ swb);
    int o1 = n16 * 8 + ((4 + quad) ^ swb);
    u16* pw = pb[w];

    f32x4 acc[4];
    float ps;
    bf16x8 qlo, qhi;
    int qrow;

    auto reset_acc = [&]() {
#pragma unroll
        for (int i = 0; i < 4; i++) acc[i] = (f32x4){0.f, 0.f, 0.f, 0.f};
        ps = 0.f;
    };
    auto load_q = [&](int qt) {
        qrow = qt * 64 + w * 16 + n16;
        const u16* qp = qkv + (b * SEQ + qrow) * 1536 + h * HD + quad * 8;
        qlo = *(const bf16x8*)qp;
        qhi = *(const bf16x8*)(qp + 32);
    };
    auto tile = [&](int kt, bool diag) {
        __syncthreads();
        const u16* kp = kbase + kt * (64 * 1536);
        const u16* vp = vbase + kt * 64;
        glds16(kp + koff0, kf + wb * 8);
        glds16(kp + koff1, kf + (256 + wb) * 8);
        glds16(vp + voff0, vf + wb * 8);
        glds16(vp + voff1, vf + (256 + wb) * 8);
        __syncthreads();
        f32x4 st[4];
#pragma unroll
        for (int nt = 0; nt < 4; nt++) {
            f32x4 sa = (f32x4){0.f, 0.f, 0.f, 0.f};
            sa = __builtin_amdgcn_mfma_f32_16x16x32_bf16(*(bf16x8*)(kf + (nt * 128 + o0) * 8), qlo, sa, 0, 0, 0);
            sa = __builtin_amdgcn_mfma_f32_16x16x32_bf16(*(bf16x8*)(kf + (nt * 128 + o1) * 8), qhi, sa, 0, 0, 0);
            st[nt] = sa;
        }
        float p[4][4];
        if (diag) {
            int kb0 = kt * 64;
#pragma unroll
            for (int nt = 0; nt < 4; nt++)
#pragma unroll
                for (int r = 0; r < 4; r++) {
                    int key = kb0 + nt * 16 + quad * 4 + r;
                    float e = exp2f(st[nt][r] + negM);
                    e = (key > qrow) ? 0.f : e;
                    p[nt][r] = e;
                    ps += e;
                }
        } else {
#pragma unroll
            for (int nt = 0; nt < 4; nt++)
#pragma unroll
                for (int r = 0; r < 4; r++) {
                    float e = exp2f(st[nt][r] + negM);
                    p[nt][r] = e;
                    ps += e;
                }
        }
#pragma unroll
        for (int nt = 0; nt < 4; nt++) {
            u32 lo = pk2t(p[nt][0], p[nt][1]);
            u32 hi = pk2t(p[nt][2], p[nt][3]);
            int ck = nt >> 1;
            int qbk = (nt & 1) * 2 + (quad >> 1);
            int byteoff = (ck * 64 + qbk * 16 + n16) * 16 + (quad & 1) * 8;
            *(uint2*)((char*)pw + byteoff) = make_uint2(lo, hi);
        }
        asm volatile("s_waitcnt lgkmcnt(0)" ::: "memory");
#pragma unroll
        for (int ck = 0; ck < 2; ck++) {
            bf16x8 pfr = *(bf16x8*)(pw + (ck * 64 + lane) * 8);
            int oo = ck ? o1 : o0;
#pragma unroll
            for (int dt = 0; dt < 4; dt++)
                acc[dt] = __builtin_amdgcn_mfma_f32_16x16x32_bf16(*(bf16x8*)(vf + (dt * 128 + oo) * 8), pfr, acc[dt], 0, 0, 0);
        }
        asm volatile("" ::: "memory");
    };
    auto write_partial = [&](int pidx) {
        float pt = ps + __shfl_xor(ps, 16, 64);
        pt += __shfl_xor(pt, 32, 64);
        if (quad == 0) psP[pidx * 64 + w * 16 + n16] = pt;
        float* ap = accP + pidx * 4096 + w * 1024;
#pragma unroll
        for (int dt = 0; dt < 4; dt++)
#pragma unroll
            for (int r = 0; r < 4; r++)
                ap[dt * 256 + quad * 64 + r * 16 + n16] = acc[dt][r];
    };

    if (role == 0) {
        load_q(qtsel);
        reset_acc();
#pragma unroll 1
        for (int kt = 0; kt < qtsel; kt++) tile(kt, false);
        tile(qtsel, true);
        {
            float pt = ps + __shfl_xor(ps, 16, 64);
            pt += __shfl_xor(pt, 32, 64);
            float li = 1.f / pt;
#pragma unroll
            for (int dt = 0; dt < 4; dt++) {
                uint2 o = make_uint2(pk2(acc[dt][0] * li, acc[dt][1] * li),
                                     pk2(acc[dt][2] * li, acc[dt][3] * li));
                int d = dt * 16 + quad * 4;
                *(uint2*)(y + (b * SEQ + qrow) * DIM + h * HD + d) = o;
            }
        }
        load_q(31 - qtsel);
        reset_acc();
#pragma unroll 1
        for (int kt = 0; kt <= 15 - qtsel; kt++) tile(kt, false);
        write_partial(pairsel * 2);
    } else {
        load_q(31 - qtsel);
        reset_acc();
#pragma unroll 1
        for (int kt = 16 - qtsel; kt < 31 - qtsel; kt++) tile(kt, false);
        tile(31 - qtsel, true);
        write_partial(pairsel * 2 + 1);
    }
}

// ---------------- K_COMB: merge split-K partials for high q-tiles ----------
__global__ __launch_bounds__(256) void k_comb(
    const float* __restrict__ accP, const float* __restrict__ psP,
    u16* __restrict__ y)
{
    int pairsel = blockIdx.x;
    int b = pairsel >> 8, h = (pairsel >> 4) & 15, qtsel = pairsel & 15;
    int qt = 31 - qtsel;
    int t = threadIdx.x, w = t >> 6, d = t & 63;
    const float* a0 = accP + (pairsel * 2) * 4096 + t * 16;
    const float* a1 = a0 + 4096;
    const float* p0 = psP + pairsel * 128 + w * 16;
    const float* p1 = p0 + 64;
    u16* yp = y + (b * SEQ + qt * 64 + w * 16) * DIM + h * HD + d;
#pragma unroll
    for (int i = 0; i < 4; i++) {
        float4 v0 = *(const float4*)(a0 + i * 4);
        float4 v1 = *(const float4*)(a1 + i * 4);
        float4 s0 = *(const float4*)(p0 + i * 4);
        float4 s1 = *(const float4*)(p1 + i * 4);
        yp[(i * 4 + 0) * DIM] = f2bf((v0.x + v1.x) / (s0.x + s1.x));
        yp[(i * 4 + 1) * DIM] = f2bf((v0.y + v1.y) / (s0.y + s1.y));
        yp[(i * 4 + 2) * DIM] = f2bf((v0.z + v1.z) / (s0.z + s1.z));
        yp[(i * 4 + 3) * DIM] = f2bf((v0.w + v1.w) / (s0.w + s1.w));
    }
}

// ---------------------------------------------------------------------------
extern "C" void kernel_launch(void* const* d_in, const int* in_sizes, int n_in,
                              void* d_out, int out_size, void* d_ws, size_t ws_size,
                              hipStream_t stream)
{
    (void)in_sizes; (void)n_in; (void)out_size; (void)ws_size;
    const float* x     = (const float*)d_in[0];
    const float* Wq    = (const float*)d_in[1];
    const float* Wk    = (const float*)d_in[2];
    const float* Wv    = (const float*)d_in[3];
    const float* Wproj = (const float*)d_in[4];
    const float* qgain = (const float*)d_in[5];
    const float* Aq    = (const float*)d_in[6];
    const float* Bq    = (const float*)d_in[7];
    const float* Av    = (const float*)d_in[8];
    const float* Bv    = (const float*)d_in[9];
    const int*   step  = (const int*)d_in[10];

    // ws layout (28.7 MB): cvt [xb 8MB | Wqkv 3MB | Wproj 2MB] + qkv 12MB +
    // tq/tv (128KB) + psP (256KB) + vt (2MB). accP (16MB fp32) in d_out
    // (dead until proj GEMM overwrites). y overlays xb (dead after qkv GEMM).
    char* ws = (char*)d_ws;
    u16* wsbf = (u16*)ws;
    u16* xb   = wsbf;
    u16* wf   = wsbf + XN;
    u16* wp   = wsbf + WV_END;
    u16* qkv  = (u16*)(ws + 13631488);
    float* tq = (float*)(ws + 26214400);
    float* tv = tq + 16384;
    float* psP = (float*)(ws + 26345472);
    u16* vt   = (u16*)(ws + 26607616);
    float* accP = (float*)d_out;
    u16* y    = xb;

    k_prep<<<CVT_BLOCKS + LORA_BLOCKS, 256, 0, stream>>>(x, Wq, Wk, Wv, Wproj, wsbf,
                                                         Aq, Av, step, tq, tv);
    k_gemm_qkv<<<768, 256, 0, stream>>>(xb, wf, qkv, vt, tq, Bq, tv, Bv, qgain, step);
    k_attn<<<1024, 256, 0, stream>>>(qkv, vt, qgain, y, accP, psP);
    k_comb<<<512, 256, 0, stream>>>(accP, psP, y);
    k_gemm_proj<<<512, 256, 0, stream>>>(y, wp, (float*)d_out);
}